// Round 2
// baseline (471.070 us; speedup 1.0000x reference)
//
#include <hip/hip_runtime.h>
#include <hip/hip_bf16.h>

#define VOCAB   65
#define NEMBD   32
#define TT      8
#define NH      4
#define HD      8
#define SQRT_C  5.656854249492381f
#define BATCHES 65536
#define ROWS    (BATCHES * TT)          // 524288 rows of logits
#define NPAIRS  (TT * VOCAB)            // 520 distinct (t, tok) combos
#define TABSZ   (NPAIRS * NEMBD)        // 16640 floats per table

// ---------------------------------------------------------------------------
// Kernel 1: precompute q/k/v tables over the 520 distinct (t, token) combos.
// qtab[(t*65+tok)*32 + h*8 + d] = sum_c (tok_emb[tok][c]+pos_emb[t][c]) * Wq[h][c][d]
// ---------------------------------------------------------------------------
__global__ void qkv_table_kernel(const float* __restrict__ tok_emb,
                                 const float* __restrict__ pos_emb,
                                 const float* __restrict__ Wq,
                                 const float* __restrict__ Wk,
                                 const float* __restrict__ Wv,
                                 float* __restrict__ qtab,
                                 float* __restrict__ ktab,
                                 float* __restrict__ vtab) {
    int o = blockIdx.x * 256 + threadIdx.x;
    if (o >= 3 * TABSZ) return;
    int table = o / TABSZ;
    int r = o - table * TABSZ;          // ((t*65+tok)*32 + h*8 + d)
    int pair = r >> 5;
    int cd = r & 31;
    int t = pair / VOCAB;
    int tok = pair - t * VOCAB;
    int h = cd >> 3, d = cd & 7;
    const float* W = (table == 0) ? Wq : (table == 1) ? Wk : Wv;
    float acc = 0.f;
    #pragma unroll
    for (int c = 0; c < 32; ++c) {
        float xc = tok_emb[tok * 32 + c] + pos_emb[t * 32 + c];
        acc += xc * W[h * 256 + c * 8 + d];
    }
    float* tab = (table == 0) ? qtab : (table == 1) ? ktab : vtab;
    tab[r] = acc;
}

// ---------------------------------------------------------------------------
// Kernel 2: fused attention + MLP + logits + loss. One wave per batch,
// grid-stride over batches; 4 waves per 256-thread block.
// ---------------------------------------------------------------------------
__global__ __launch_bounds__(256) void fused_kernel(
        const int* __restrict__ idx, const int* __restrict__ targets,
        const float* __restrict__ qtab, const float* __restrict__ ktab,
        const float* __restrict__ vtab,
        const float* __restrict__ W_mlp,
        const float* __restrict__ b_mlp,
        const float* __restrict__ W_lm,
        const float* __restrict__ b_lm,
        float* __restrict__ out_logits,
        float* __restrict__ loss_acc) {
    // per-wave LDS regions; q/k/v stored as [h][t][d] with h-stride 72 (pad
    // breaks bank aliasing across h while keeping 16B alignment: 72*4=288B)
    __shared__ __align__(16) float sQ[4][288];
    __shared__ __align__(16) float sK[4][288];
    __shared__ __align__(16) float sV[4][288];
    __shared__ __align__(16) float sX2[4][256];   // [t][c] post-attention concat
    __shared__ __align__(16) float sX3[4][256];   // [t][j] post-MLP
    __shared__ __align__(16) float sW64[32];      // W_lm[:,64]

    const int tid = threadIdx.x;
    const int w = tid >> 6;       // wave in block
    const int l = tid & 63;       // lane

    if (tid < 32) sW64[tid] = W_lm[tid * VOCAB + 64];

    // per-lane cached weight columns (amortized over 8 batches/wave)
    const int j = l & 31;
    float wc[32], wl[32];
    #pragma unroll
    for (int c = 0; c < 32; ++c) wc[c] = W_mlp[c * 32 + j];      // W_mlp[:,j]
    #pragma unroll
    for (int c = 0; c < 32; ++c) wl[c] = W_lm[c * VOCAB + l];    // W_lm[:,l]
    const float bm   = b_mlp[j];
    const float bl   = b_lm[l];
    const float bl64 = b_lm[64];

    __syncthreads();

    float loss_local = 0.f;
    const int nwaves = gridDim.x * 4;
    const int wave_id = blockIdx.x * 4 + w;

    for (int b = wave_id; b < BATCHES; b += nwaves) {
        const int tokv = idx[b * 8 + (l & 7)];       // lane holds idx[b][l&7]
        const int tgv  = targets[b * 8 + (l & 7)];

        // ---- gather q,k,v rows (float4 per lane per table) into LDS ----
        {
            int t = l >> 3, c4 = l & 7;
            int tok_t = __shfl(tokv, t);
            int base = (t * VOCAB + tok_t) * 32 + c4 * 4;
            int h = c4 >> 1;
            int laddr = h * 72 + t * 8 + (c4 & 1) * 4;
            float4 q4 = *(const float4*)(qtab + base);
            float4 k4 = *(const float4*)(ktab + base);
            float4 v4 = *(const float4*)(vtab + base);
            *(float4*)(&sQ[w][laddr]) = q4;
            *(float4*)(&sK[w][laddr]) = k4;
            *(float4*)(&sV[w][laddr]) = v4;
        }
        __syncthreads();

        // ---- attention: lanes 0..31, one (h,t) row each ----
        if (l < 32) {
            int h = l >> 3, t = l & 7;
            const float4 q0 = *(const float4*)(&sQ[w][h * 72 + t * 8]);
            const float4 q1 = *(const float4*)(&sQ[w][h * 72 + t * 8 + 4]);
            float sc[8], m = -1e30f;
            #pragma unroll
            for (int s = 0; s < 8; ++s) {
                float4 k0 = *(const float4*)(&sK[w][h * 72 + s * 8]);
                float4 k1 = *(const float4*)(&sK[w][h * 72 + s * 8 + 4]);
                float d = q0.x * k0.x + q0.y * k0.y + q0.z * k0.z + q0.w * k0.w
                        + q1.x * k1.x + q1.y * k1.y + q1.z * k1.z + q1.w * k1.w;
                d *= SQRT_C;                     // faithful bug: * sqrt(C)
                sc[s] = d;
                if (s <= t) m = fmaxf(m, d);
            }
            float p[8], sum = 0.f;
            #pragma unroll
            for (int s = 0; s < 8; ++s) {
                p[s] = (s <= t) ? __expf(sc[s] - m) : 0.f;
                sum += p[s];
            }
            float inv = 1.f / sum;
            float o0x = 0, o0y = 0, o0z = 0, o0w = 0, o1x = 0, o1y = 0, o1z = 0, o1w = 0;
            #pragma unroll
            for (int s = 0; s < 8; ++s) {
                float4 v0 = *(const float4*)(&sV[w][h * 72 + s * 8]);
                float4 v1 = *(const float4*)(&sV[w][h * 72 + s * 8 + 4]);
                o0x += p[s] * v0.x; o0y += p[s] * v0.y; o0z += p[s] * v0.z; o0w += p[s] * v0.w;
                o1x += p[s] * v1.x; o1y += p[s] * v1.y; o1z += p[s] * v1.z; o1w += p[s] * v1.w;
            }
            float4 r0 = make_float4(o0x * inv, o0y * inv, o0z * inv, o0w * inv);
            float4 r1 = make_float4(o1x * inv, o1y * inv, o1z * inv, o1w * inv);
            *(float4*)(&sX2[w][t * 32 + h * 8]) = r0;
            *(float4*)(&sX2[w][t * 32 + h * 8 + 4]) = r1;
        }
        __syncthreads();

        // ---- MLP: 256 outputs (t,j); lane l -> j=l&31, t covers 0..7 ----
        #pragma unroll
        for (int i = 0; i < 4; ++i) {
            int flat = i * 64 + l;
            int t = flat >> 5;
            float acc = bm;
            #pragma unroll
            for (int c4 = 0; c4 < 8; ++c4) {
                float4 xv = *(const float4*)(&sX2[w][t * 32 + c4 * 4]);
                acc += xv.x * wc[c4 * 4 + 0] + xv.y * wc[c4 * 4 + 1]
                     + xv.z * wc[c4 * 4 + 2] + xv.w * wc[c4 * 4 + 3];
            }
            sX3[w][flat] = fmaxf(acc, 0.f);
        }
        __syncthreads();

        // ---- logits + loss, per t: lane l computes column l, all compute col 64 ----
        for (int t = 0; t < 8; ++t) {
            float L = bl, L64 = bl64;
            #pragma unroll
            for (int c4 = 0; c4 < 8; ++c4) {
                float4 xv = *(const float4*)(&sX3[w][t * 32 + c4 * 4]);
                float4 wv = *(const float4*)(&sW64[c4 * 4]);
                L   += xv.x * wl[c4 * 4 + 0] + xv.y * wl[c4 * 4 + 1]
                     + xv.z * wl[c4 * 4 + 2] + xv.w * wl[c4 * 4 + 3];
                L64 += xv.x * wv.x + xv.y * wv.y + xv.z * wv.z + xv.w * wv.w;
            }
            size_t rowbase = (size_t)(b * 8 + t) * VOCAB;
            out_logits[rowbase + l] = L;
            if (l == 0) out_logits[rowbase + 64] = L64;

            // wave-wide logsumexp over 65 entries (col 64 counted once)
            float mloc = fmaxf(L, L64);
            #pragma unroll
            for (int off = 1; off < 64; off <<= 1) mloc = fmaxf(mloc, __shfl_xor(mloc, off));
            float sloc = __expf(L - mloc) + ((l == 0) ? __expf(L64 - mloc) : 0.f);
            #pragma unroll
            for (int off = 1; off < 64; off <<= 1) sloc += __shfl_xor(sloc, off);
            int tg = __shfl(tgv, t);
            float ltgt = (tg == 64) ? L64 : __shfl(L, tg);
            loss_local += (mloc + __logf(sloc)) - ltgt;
        }
        __syncthreads();
    }

    if (l == 0) atomicAdd(loss_acc, loss_local);
}

__global__ void finalize_loss(const float* __restrict__ acc,
                              float* __restrict__ out) {
    out[0] = acc[0] * (1.f / (float)ROWS);
}

extern "C" void kernel_launch(void* const* d_in, const int* in_sizes, int n_in,
                              void* d_out, int out_size, void* d_ws, size_t ws_size,
                              hipStream_t stream) {
    const int* idx        = (const int*)d_in[0];
    const int* targets    = (const int*)d_in[1];
    const float* tok_emb  = (const float*)d_in[2];
    const float* pos_emb  = (const float*)d_in[3];
    const float* Wq       = (const float*)d_in[4];
    const float* Wk       = (const float*)d_in[5];
    const float* Wv       = (const float*)d_in[6];
    const float* W_mlp    = (const float*)d_in[7];
    const float* b_mlp    = (const float*)d_in[8];
    const float* W_lm     = (const float*)d_in[9];
    const float* b_lm     = (const float*)d_in[10];
    float* out            = (float*)d_out;

    float* ws       = (float*)d_ws;
    float* loss_ptr = ws;                 // 1 float accumulator
    float* qtab     = ws + 16;            // 64B-aligned offset
    float* ktab     = qtab + TABSZ;
    float* vtab     = ktab + TABSZ;

    hipMemsetAsync(loss_ptr, 0, sizeof(float), stream);

    qkv_table_kernel<<<(3 * TABSZ + 255) / 256, 256, 0, stream>>>(
        tok_emb, pos_emb, Wq, Wk, Wv, qtab, ktab, vtab);

    fused_kernel<<<2048, 256, 0, stream>>>(
        idx, targets, qtab, ktab, vtab, W_mlp, b_mlp, W_lm, b_lm, out, loss_ptr);

    finalize_loss<<<1, 1, 0, stream>>>(loss_ptr, out + (size_t)ROWS * VOCAB);
}

// Round 3
// 369.748 us; speedup vs baseline: 1.2740x; 1.2740x over previous
//
#include <hip/hip_runtime.h>
#include <hip/hip_bf16.h>

#define VOCAB   65
#define SQRT_C  5.656854249492381f
#define BATCHES 65536
#define ROWS    (BATCHES * 8)          // 524288 rows of logits
#define NPAIRS  (8 * VOCAB)            // 520 distinct (t, tok) combos
#define TABSZ   (NPAIRS * 32)          // 16640 floats per table
#define PAIRS   (BATCHES / 2)          // 32768 batch-pairs
#define GRID    8192

__device__ __forceinline__ void wave_fence() {
    // single-wave workgroup: drain LDS ops + forbid compiler reordering.
    __asm__ volatile("s_waitcnt lgkmcnt(0)" ::: "memory");
}

// ---------------------------------------------------------------------------
// Kernel 1: precompute q/k/v tables over the 520 distinct (t, token) combos.
// ---------------------------------------------------------------------------
__global__ void qkv_table_kernel(const float* __restrict__ tok_emb,
                                 const float* __restrict__ pos_emb,
                                 const float* __restrict__ Wq,
                                 const float* __restrict__ Wk,
                                 const float* __restrict__ Wv,
                                 float* __restrict__ qtab,
                                 float* __restrict__ ktab,
                                 float* __restrict__ vtab) {
    int o = blockIdx.x * 256 + threadIdx.x;
    if (o >= 3 * TABSZ) return;
    int table = o / TABSZ;
    int r = o - table * TABSZ;          // ((t*65+tok)*32 + h*8 + d)
    int pair = r >> 5;
    int cd = r & 31;
    int t = pair / VOCAB;
    int tok = pair - t * VOCAB;
    int h = cd >> 3, d = cd & 7;
    const float* W = (table == 0) ? Wq : (table == 1) ? Wk : Wv;
    float acc = 0.f;
    #pragma unroll
    for (int c = 0; c < 32; ++c) {
        float xc = tok_emb[tok * 32 + c] + pos_emb[t * 32 + c];
        acc += xc * W[h * 256 + c * 8 + d];
    }
    float* tab = (table == 0) ? qtab : (table == 1) ? ktab : vtab;
    tab[r] = acc;
}

// ---------------------------------------------------------------------------
// Kernel 2: one 64-lane wave per workgroup; each iteration processes TWO
// batches (lanes 0-31 = batch A contexts, 32-63 = batch B). No __syncthreads
// anywhere in the loop — only intra-wave lgkmcnt fences.
// ---------------------------------------------------------------------------
__global__ __launch_bounds__(64) void fused_kernel(
        const int* __restrict__ idx, const int* __restrict__ targets,
        const float* __restrict__ qtab, const float* __restrict__ ktab,
        const float* __restrict__ vtab,
        const float* __restrict__ W_mlp,
        const float* __restrict__ b_mlp,
        const float* __restrict__ W_lm,
        const float* __restrict__ b_lm,
        float* __restrict__ out_logits,
        float* __restrict__ loss_acc) {
    // q/k/v: [b2][h][t][d], h-stride 72 (pad); x2/x3: [b2][t][c], t-stride 36
    __shared__ __align__(16) float sQ[576];
    __shared__ __align__(16) float sK[576];
    __shared__ __align__(16) float sV[576];
    __shared__ __align__(16) float sX2[576];
    __shared__ __align__(16) float sX3[576];
    __shared__ __align__(16) float sW64[32];

    const int l = threadIdx.x;

    if (l < 32) sW64[l] = W_lm[l * VOCAB + 64];

    // per-lane cached weight columns (persist across all iterations)
    const int j = l & 31;
    float wc[32], wl[32];
    #pragma unroll
    for (int c = 0; c < 32; ++c) wc[c] = W_mlp[c * 32 + j];      // W_mlp[:,j]
    #pragma unroll
    for (int c = 0; c < 32; ++c) wl[c] = W_lm[c * VOCAB + l];    // W_lm[:,l]
    const float bm   = b_mlp[j];
    const float bl   = b_lm[l];
    const float bl64 = b_lm[64];
    wave_fence();

    float loss_local = 0.f;

    for (int pb = blockIdx.x; pb < PAIRS; pb += GRID) {
        // lanes 0..15 hold idx/targets for the two batches (b2 = l>>3, t = l&7)
        int tokv = 0, tgv = 0;
        if (l < 16) { tokv = idx[pb * 16 + l]; tgv = targets[pb * 16 + l]; }

        // ---- gather q,k,v into LDS: 6 full-wave float4 loads ----
        {
            int t = l >> 3, c4 = l & 7;
            int h = c4 >> 1;
            int la = h * 72 + t * 8 + (c4 & 1) * 4;
            #pragma unroll
            for (int b2 = 0; b2 < 2; ++b2) {
                int tok_t = __shfl(tokv, b2 * 8 + t);
                int base = (t * VOCAB + tok_t) * 32 + c4 * 4;
                int laddr = b2 * 288 + la;
                *(float4*)(sQ + laddr) = *(const float4*)(qtab + base);
                *(float4*)(sK + laddr) = *(const float4*)(ktab + base);
                *(float4*)(sV + laddr) = *(const float4*)(vtab + base);
            }
        }
        wave_fence();

        // ---- attention: all 64 lanes, one (b2,h,t) row each ----
        {
            int b2 = l >> 5, h = (l >> 3) & 3, t = l & 7;
            int hb = b2 * 288 + h * 72;
            const float4 q0 = *(const float4*)(sQ + hb + t * 8);
            const float4 q1 = *(const float4*)(sQ + hb + t * 8 + 4);
            float sc[8], m = -1e30f;
            #pragma unroll
            for (int s = 0; s < 8; ++s) {
                float4 k0 = *(const float4*)(sK + hb + s * 8);
                float4 k1 = *(const float4*)(sK + hb + s * 8 + 4);
                float d = q0.x * k0.x + q0.y * k0.y + q0.z * k0.z + q0.w * k0.w
                        + q1.x * k1.x + q1.y * k1.y + q1.z * k1.z + q1.w * k1.w;
                d *= SQRT_C;                     // faithful bug: * sqrt(C)
                sc[s] = d;
                if (s <= t) m = fmaxf(m, d);
            }
            float p[8], sum = 0.f;
            #pragma unroll
            for (int s = 0; s < 8; ++s) {
                p[s] = (s <= t) ? __expf(sc[s] - m) : 0.f;
                sum += p[s];
            }
            float inv = 1.f / sum;
            float o0x = 0, o0y = 0, o0z = 0, o0w = 0, o1x = 0, o1y = 0, o1z = 0, o1w = 0;
            #pragma unroll
            for (int s = 0; s < 8; ++s) {
                float4 v0 = *(const float4*)(sV + hb + s * 8);
                float4 v1 = *(const float4*)(sV + hb + s * 8 + 4);
                o0x += p[s] * v0.x; o0y += p[s] * v0.y; o0z += p[s] * v0.z; o0w += p[s] * v0.w;
                o1x += p[s] * v1.x; o1y += p[s] * v1.y; o1z += p[s] * v1.z; o1w += p[s] * v1.w;
            }
            int xb = b2 * 288 + t * 36 + h * 8;
            *(float4*)(sX2 + xb)     = make_float4(o0x * inv, o0y * inv, o0z * inv, o0w * inv);
            *(float4*)(sX2 + xb + 4) = make_float4(o1x * inv, o1y * inv, o1z * inv, o1w * inv);
        }
        wave_fence();

        // ---- MLP: 512 outputs over 8 iterations; j = l&31 matches wc ----
        #pragma unroll
        for (int i = 0; i < 8; ++i) {
            int flat = i * 64 + l;
            int b2 = flat >> 8, t = (flat >> 5) & 7;
            int xb = b2 * 288 + t * 36;
            float acc = bm;
            #pragma unroll
            for (int c4 = 0; c4 < 8; ++c4) {
                float4 xv = *(const float4*)(sX2 + xb + c4 * 4);
                acc += xv.x * wc[c4 * 4 + 0] + xv.y * wc[c4 * 4 + 1]
                     + xv.z * wc[c4 * 4 + 2] + xv.w * wc[c4 * 4 + 3];
            }
            sX3[b2 * 288 + t * 36 + j] = fmaxf(acc, 0.f);
        }
        wave_fence();

        // ---- column-64 logits: lanes 0..15 own one row each (others dup) ----
        float L64own;
        {
            int rr = l & 15;
            int xb = (rr >> 3) * 288 + (rr & 7) * 36;
            float acc = bl64;
            #pragma unroll
            for (int c4 = 0; c4 < 8; ++c4) {
                float4 xv = *(const float4*)(sX3 + xb + c4 * 4);
                float4 wv = *(const float4*)(sW64 + c4 * 4);
                acc += xv.x * wv.x + xv.y * wv.y + xv.z * wv.z + xv.w * wv.w;
            }
            L64own = acc;
        }
        if (l < 16) out_logits[(size_t)(pb * 16 + l) * VOCAB + 64] = L64own;

        // ---- logits cols 0..63 + batched loss, one 8-row group per batch ----
        #pragma unroll
        for (int g = 0; g < 2; ++g) {
            float Lr[8];
            #pragma unroll
            for (int r = 0; r < 8; ++r) {
                int xb = g * 288 + r * 36;
                float acc = bl;
                #pragma unroll
                for (int c4 = 0; c4 < 8; ++c4) {
                    float4 xv = *(const float4*)(sX3 + xb + c4 * 4);
                    acc += xv.x * wl[c4 * 4 + 0] + xv.y * wl[c4 * 4 + 1]
                         + xv.z * wl[c4 * 4 + 2] + xv.w * wl[c4 * 4 + 3];
                }
                Lr[r] = acc;
                out_logits[(size_t)(pb * 16 + g * 8 + r) * VOCAB + l] = acc;
            }
            // interleaved 8-wide reductions (independent chains pipeline)
            float m[8], v64[8], ltg[8], s[8];
            #pragma unroll
            for (int r = 0; r < 8; ++r) m[r] = Lr[r];
            #pragma unroll
            for (int off = 1; off < 64; off <<= 1) {
                #pragma unroll
                for (int r = 0; r < 8; ++r) m[r] = fmaxf(m[r], __shfl_xor(m[r], off));
            }
            #pragma unroll
            for (int r = 0; r < 8; ++r) {
                v64[r] = __shfl(L64own, g * 8 + r);
                m[r] = fmaxf(m[r], v64[r]);
            }
            #pragma unroll
            for (int r = 0; r < 8; ++r) {
                int tg = __shfl(tgv, g * 8 + r);
                ltg[r] = (tg == 64) ? v64[r] : __shfl(Lr[r], tg);
            }
            #pragma unroll
            for (int r = 0; r < 8; ++r) s[r] = __expf(Lr[r] - m[r]);
            #pragma unroll
            for (int off = 1; off < 64; off <<= 1) {
                #pragma unroll
                for (int r = 0; r < 8; ++r) s[r] += __shfl_xor(s[r], off);
            }
            #pragma unroll
            for (int r = 0; r < 8; ++r) {
                s[r] += __expf(v64[r] - m[r]);
                loss_local += m[r] + __logf(s[r]) - ltg[r];
            }
        }
    }

    if (l == 0) atomicAdd(loss_acc, loss_local);
}

__global__ void finalize_loss(const float* __restrict__ acc,
                              float* __restrict__ out) {
    out[0] = acc[0] * (1.f / (float)ROWS);
}

extern "C" void kernel_launch(void* const* d_in, const int* in_sizes, int n_in,
                              void* d_out, int out_size, void* d_ws, size_t ws_size,
                              hipStream_t stream) {
    const int* idx        = (const int*)d_in[0];
    const int* targets    = (const int*)d_in[1];
    const float* tok_emb  = (const float*)d_in[2];
    const float* pos_emb  = (const float*)d_in[3];
    const float* Wq       = (const float*)d_in[4];
    const float* Wk       = (const float*)d_in[5];
    const float* Wv       = (const float*)d_in[6];
    const float* W_mlp    = (const float*)d_in[7];
    const float* b_mlp    = (const float*)d_in[8];
    const float* W_lm     = (const float*)d_in[9];
    const float* b_lm     = (const float*)d_in[10];
    float* out            = (float*)d_out;

    float* ws       = (float*)d_ws;
    float* loss_ptr = ws;                 // 1 float accumulator
    float* qtab     = ws + 16;            // 64B-aligned offset
    float* ktab     = qtab + TABSZ;
    float* vtab     = ktab + TABSZ;

    hipMemsetAsync(loss_ptr, 0, sizeof(float), stream);

    qkv_table_kernel<<<(3 * TABSZ + 255) / 256, 256, 0, stream>>>(
        tok_emb, pos_emb, Wq, Wk, Wv, qtab, ktab, vtab);

    fused_kernel<<<GRID, 64, 0, stream>>>(
        idx, targets, qtab, ktab, vtab, W_mlp, b_mlp, W_lm, b_lm, out, loss_ptr);

    finalize_loss<<<1, 1, 0, stream>>>(loss_ptr, out + (size_t)ROWS * VOCAB);
}

// Round 4
// 313.563 us; speedup vs baseline: 1.5023x; 1.1792x over previous
//
#include <hip/hip_runtime.h>
#include <hip/hip_bf16.h>

#define VOCAB   65
#define SQRT_C  5.656854249492381f
#define BATCHES 65536
#define ROWS    (BATCHES * 8)
#define TABSZ   (8 * VOCAB * 32)       // 16640 floats per q/k/v table
#define PAIRS   (BATCHES / 2)          // 32768 batch-pairs (16 rows each)
#define NBLOCKS 2048
#define NWAVES  (NBLOCKS * 4)

typedef __attribute__((ext_vector_type(8))) short  short8;   // 8 bf16 = 4 VGPRs
typedef __attribute__((ext_vector_type(4))) float  float4v;  // MFMA C/D

__device__ __forceinline__ void wave_fence() {
    __asm__ volatile("s_waitcnt lgkmcnt(0)" ::: "memory");
}
__device__ __forceinline__ short bfbits(float f) {
    __hip_bfloat16 h = __float2bfloat16(f);
    return *reinterpret_cast<short*>(&h);
}

// ---------------------------------------------------------------------------
// Kernel 1: precompute q/k/v tables over the 520 distinct (t, token) combos.
// tab[(t*65+tok)*32 + h*8 + d]
// ---------------------------------------------------------------------------
__global__ void qkv_table_kernel(const float* __restrict__ tok_emb,
                                 const float* __restrict__ pos_emb,
                                 const float* __restrict__ Wq,
                                 const float* __restrict__ Wk,
                                 const float* __restrict__ Wv,
                                 float* __restrict__ qtab,
                                 float* __restrict__ ktab,
                                 float* __restrict__ vtab) {
    int o = blockIdx.x * 256 + threadIdx.x;
    if (o >= 3 * TABSZ) return;
    int table = o / TABSZ;
    int r = o - table * TABSZ;
    int pair = r >> 5;
    int cd = r & 31;
    int t = pair / VOCAB;
    int tok = pair - t * VOCAB;
    int h = cd >> 3, d = cd & 7;
    const float* W = (table == 0) ? Wq : (table == 1) ? Wk : Wv;
    float acc = 0.f;
    #pragma unroll
    for (int c = 0; c < 32; ++c) {
        float xc = tok_emb[tok * 32 + c] + pos_emb[t * 32 + c];
        acc += xc * W[h * 256 + c * 8 + d];
    }
    float* tab = (table == 0) ? qtab : (table == 1) ? ktab : vtab;
    tab[r] = acc;
}

// ---------------------------------------------------------------------------
// Kernel 2: 4 independent waves per 256-block; each wave owns one batch-pair
// (16 logit rows) per iteration. Attention on VALU; MLP + logits + target
// logit via bf16 MFMA 16x16x32. No __syncthreads in the loop.
// ---------------------------------------------------------------------------
__global__ __launch_bounds__(256) void fused_kernel(
        const int* __restrict__ idx, const int* __restrict__ targets,
        const float* __restrict__ qtab, const float* __restrict__ ktab,
        const float* __restrict__ vtab,
        const float* __restrict__ W_mlp,
        const float* __restrict__ b_mlp,
        const float* __restrict__ W_lm,
        const float* __restrict__ b_lm,
        float* __restrict__ out_logits,
        float* __restrict__ loss_acc) {
    // per-wave K/V: [grp=h*2+b2][s][d], grp-stride 68 words (conflict-free
    // 8-group broadcast: 68%32=4 -> groups start 4 banks apart)
    __shared__ __align__(16) float sK[4][544];
    __shared__ __align__(16) float sV[4][544];
    // per-wave x3 bf16 [row][ch], row-stride 40 shorts (80B, 16B-aligned)
    __shared__ __align__(16) unsigned short sX3[4][640];

    const int tid = threadIdx.x;
    const int w = tid >> 6, l = tid & 63;
    const int q4 = l >> 4;        // MFMA quad
    const int n  = l & 15;        // MFMA col-lane
    const int t  = l & 7, b2 = (l >> 3) & 1, h = q4;   // attention identity

    // ---- persistent B-fragments: B[k=(q4*8+j)][n] ----
    short8 wmf[2], wlf[4], wlf4;
    #pragma unroll
    for (int c = 0; c < 2; ++c)
        #pragma unroll
        for (int j = 0; j < 8; ++j)
            wmf[c][j] = bfbits(W_mlp[(q4 * 8 + j) * 32 + c * 16 + n]);
    #pragma unroll
    for (int c = 0; c < 4; ++c)
        #pragma unroll
        for (int j = 0; j < 8; ++j)
            wlf[c][j] = bfbits(W_lm[(q4 * 8 + j) * VOCAB + c * 16 + n]);
    #pragma unroll
    for (int j = 0; j < 8; ++j)
        wlf4[j] = (n == 0) ? bfbits(W_lm[(q4 * 8 + j) * VOCAB + 64]) : (short)0;
    float bmc[2], blc[4];
    #pragma unroll
    for (int c = 0; c < 2; ++c) bmc[c] = b_mlp[c * 16 + n];
    #pragma unroll
    for (int c = 0; c < 4; ++c) blc[c] = b_lm[c * 16 + n];
    const float bl64 = b_lm[64];
    const float4v zf = {0.f, 0.f, 0.f, 0.f};

    float loss_local = 0.f;

    for (int pb = blockIdx.x * 4 + w; pb < PAIRS; pb += NWAVES) {
        int tokv = 0, tgv = 0;
        if (l < 16) { tokv = idx[pb * 16 + l]; tgv = targets[pb * 16 + l]; }

        // ---- gather K/V into LDS: 2 float4 chunks per table per lane ----
        #pragma unroll
        for (int half = 0; half < 2; ++half) {
            int c = l + half * 64;
            int d2 = c & 1, s = (c >> 1) & 7, grp = c >> 4;   // grp 0..7
            int b2g = grp & 1, hg = grp >> 1;
            int tok_s = __shfl(tokv, b2g * 8 + s);
            int gaddr = (s * VOCAB + tok_s) * 32 + hg * 8 + d2 * 4;
            int laddr = grp * 68 + s * 8 + d2 * 4;
            *(float4*)(&sK[w][laddr]) = *(const float4*)(ktab + gaddr);
            *(float4*)(&sV[w][laddr]) = *(const float4*)(vtab + gaddr);
        }
        // own q row straight from global (L2-resident table)
        int tok_t = __shfl(tokv, b2 * 8 + t);
        const float* qp = qtab + (t * VOCAB + tok_t) * 32 + h * 8;
        const float4 q0 = *(const float4*)(qp);
        const float4 q1 = *(const float4*)(qp + 4);
        wave_fence();

        // ---- attention (fp32): lane (b2,h,t); out regs land in A-layout ----
        const float* kb = &sK[w][(h * 2 + b2) * 68];
        const float* vb = &sV[w][(h * 2 + b2) * 68];
        float sc[8], m = -1e30f;
        #pragma unroll
        for (int s = 0; s < 8; ++s) {
            float4 k0 = *(const float4*)(kb + s * 8);
            float4 k1 = *(const float4*)(kb + s * 8 + 4);
            float d = q0.x * k0.x + q0.y * k0.y + q0.z * k0.z + q0.w * k0.w
                    + q1.x * k1.x + q1.y * k1.y + q1.z * k1.z + q1.w * k1.w;
            d *= SQRT_C;                         // faithful bug: * sqrt(C)
            sc[s] = d;
            if (s <= t) m = fmaxf(m, d);
        }
        float p[8], sum = 0.f;
        #pragma unroll
        for (int s = 0; s < 8; ++s) {
            p[s] = (s <= t) ? __expf(sc[s] - m) : 0.f;
            sum += p[s];
        }
        float inv = 1.f / sum;
        float o[8];
        #pragma unroll
        for (int d = 0; d < 8; ++d) o[d] = 0.f;
        #pragma unroll
        for (int s = 0; s < 8; ++s) {
            float4 v0 = *(const float4*)(vb + s * 8);
            float4 v1 = *(const float4*)(vb + s * 8 + 4);
            o[0] += p[s] * v0.x; o[1] += p[s] * v0.y; o[2] += p[s] * v0.z; o[3] += p[s] * v0.w;
            o[4] += p[s] * v1.x; o[5] += p[s] * v1.y; o[6] += p[s] * v1.z; o[7] += p[s] * v1.w;
        }
        short8 a2;
        #pragma unroll
        for (int d = 0; d < 8; ++d) a2[d] = bfbits(o[d] * inv);

        // ---- MLP: x3 = relu(x2 @ W_mlp + b), 2 MFMAs ----
        float4v d0 = __builtin_amdgcn_mfma_f32_16x16x32_bf16(a2, wmf[0], zf, 0, 0, 0);
        float4v d1 = __builtin_amdgcn_mfma_f32_16x16x32_bf16(a2, wmf[1], zf, 0, 0, 0);
        #pragma unroll
        for (int i = 0; i < 4; ++i) {
            int row = q4 * 4 + i;
            sX3[w][row * 40 + n]      = (unsigned short)bfbits(fmaxf(d0[i] + bmc[0], 0.f));
            sX3[w][row * 40 + 16 + n] = (unsigned short)bfbits(fmaxf(d1[i] + bmc[1], 0.f));
        }
        wave_fence();
        // C->A transpose via LDS: one b128 read
        short8 a3 = *(const short8*)(&sX3[w][n * 40 + q4 * 8]);

        // ---- target-column B fragment: B6[k][n] = W_lm[k][tg_n] ----
        int tgn = __shfl(tgv, n);
        short8 b6;
        #pragma unroll
        for (int j = 0; j < 8; ++j) b6[j] = bfbits(W_lm[(q4 * 8 + j) * VOCAB + tgn]);
        float btg = b_lm[tgn];

        // ---- logits: 6 MFMAs ----
        float4v Lc[4];
        #pragma unroll
        for (int c = 0; c < 4; ++c)
            Lc[c] = __builtin_amdgcn_mfma_f32_16x16x32_bf16(a3, wlf[c], zf, 0, 0, 0);
        float4v L64 = __builtin_amdgcn_mfma_f32_16x16x32_bf16(a3, wlf4, zf, 0, 0, 0);
        float4v Ltg = __builtin_amdgcn_mfma_f32_16x16x32_bf16(a3, b6, zf, 0, 0, 0);

        // ---- bias + store + sum-exp (no max-subtract: |logits| << 88) ----
        size_t rb = (size_t)pb * 16;
        float part[4] = {0.f, 0.f, 0.f, 0.f};
        #pragma unroll
        for (int c = 0; c < 4; ++c) {
            #pragma unroll
            for (int i = 0; i < 4; ++i) {
                float Lv = Lc[c][i] + blc[c];
                out_logits[(rb + q4 * 4 + i) * VOCAB + c * 16 + n] = Lv;
                part[i] += __expf(Lv);
            }
        }
        if (n == 0) {
            #pragma unroll
            for (int i = 0; i < 4; ++i) {
                float Lv = L64[i] + bl64;
                out_logits[(rb + q4 * 4 + i) * VOCAB + 64] = Lv;
                part[i] += __expf(Lv);
            }
        }
        #pragma unroll
        for (int off = 1; off < 16; off <<= 1) {
            #pragma unroll
            for (int i = 0; i < 4; ++i) part[i] += __shfl_xor(part[i], off);
        }
        float lg = __logf(part[0]) + __logf(part[1]) + __logf(part[2]) + __logf(part[3]);
        if (n == 0) loss_local += lg;              // 4 lanes cover 16 rows
        int rd = n - q4 * 4;                       // diagonal of Ltg = target logit
        float tval = (rd == 0) ? Ltg[0] : (rd == 1) ? Ltg[1] : (rd == 2) ? Ltg[2] : Ltg[3];
        if (rd >= 0 && rd <= 3) loss_local -= (tval + btg);
    }

    #pragma unroll
    for (int off = 1; off < 64; off <<= 1) loss_local += __shfl_xor(loss_local, off);
    if (l == 0) atomicAdd(loss_acc, loss_local);
}

__global__ void finalize_loss(const float* __restrict__ acc,
                              float* __restrict__ out) {
    out[0] = acc[0] * (1.f / (float)ROWS);
}

extern "C" void kernel_launch(void* const* d_in, const int* in_sizes, int n_in,
                              void* d_out, int out_size, void* d_ws, size_t ws_size,
                              hipStream_t stream) {
    const int* idx        = (const int*)d_in[0];
    const int* targets    = (const int*)d_in[1];
    const float* tok_emb  = (const float*)d_in[2];
    const float* pos_emb  = (const float*)d_in[3];
    const float* Wq       = (const float*)d_in[4];
    const float* Wk       = (const float*)d_in[5];
    const float* Wv       = (const float*)d_in[6];
    const float* W_mlp    = (const float*)d_in[7];
    const float* b_mlp    = (const float*)d_in[8];
    const float* W_lm     = (const float*)d_in[9];
    const float* b_lm     = (const float*)d_in[10];
    float* out            = (float*)d_out;

    float* ws       = (float*)d_ws;
    float* loss_ptr = ws;
    float* qtab     = ws + 16;
    float* ktab     = qtab + TABSZ;
    float* vtab     = ktab + TABSZ;

    hipMemsetAsync(loss_ptr, 0, sizeof(float), stream);

    qkv_table_kernel<<<(3 * TABSZ + 255) / 256, 256, 0, stream>>>(
        tok_emb, pos_emb, Wq, Wk, Wv, qtab, ktab, vtab);

    fused_kernel<<<NBLOCKS, 256, 0, stream>>>(
        idx, targets, qtab, ktab, vtab, W_mlp, b_mlp, W_lm, b_lm, out, loss_ptr);

    finalize_loss<<<1, 1, 0, stream>>>(loss_ptr, out + (size_t)ROWS * VOCAB);
}